// Round 1
// baseline (88.270 us; speedup 1.0000x reference)
//
#include <hip/hip_runtime.h>
#include <math.h>

// EdgeWeightLearner:
//   p_row[n] = dot(x[n], w_lin[0:64]);  p_col[n] = dot(x[n], w_lin[64:128])
//   weights[e] = sigmoid(p_row[row[e]] + p_col[col[e]])
//   out[e] = weights[e] * weights[fri[e]]

#define IN_CH 64

// Kernel 1: per-node dot products. 16 lanes per node, float4 each -> 64 ch.
__global__ void node_dots_kernel(const float* __restrict__ x,
                                 const float* __restrict__ w_lin,
                                 float* __restrict__ p_row,
                                 float* __restrict__ p_col,
                                 int n_nodes) {
    int tid = blockIdx.x * blockDim.x + threadIdx.x;
    int node = tid >> 4;
    int sub  = tid & 15;
    if (node >= n_nodes) return;
    const float4 xv = *reinterpret_cast<const float4*>(x + node * IN_CH + sub * 4);
    const float4 wr = *reinterpret_cast<const float4*>(w_lin + sub * 4);
    const float4 wc = *reinterpret_cast<const float4*>(w_lin + IN_CH + sub * 4);
    float pr = xv.x * wr.x + xv.y * wr.y + xv.z * wr.z + xv.w * wr.w;
    float pc = xv.x * wc.x + xv.y * wc.y + xv.z * wc.z + xv.w * wc.w;
    // reduce across the 16-lane group (xor masks 1,2,4,8 stay in-group)
    #pragma unroll
    for (int m = 1; m < 16; m <<= 1) {
        pr += __shfl_xor(pr, m, 64);
        pc += __shfl_xor(pc, m, 64);
    }
    if (sub == 0) {
        p_row[node] = pr;
        p_col[node] = pc;
    }
}

// Kernel 2: per-edge sigmoid of gathered node dots. 4 edges/thread.
__global__ void edge_sigmoid_kernel(const int* __restrict__ row,
                                    const int* __restrict__ col,
                                    const float* __restrict__ p_row,
                                    const float* __restrict__ p_col,
                                    float* __restrict__ weights,
                                    int n_edges) {
    int e0 = (blockIdx.x * blockDim.x + threadIdx.x) * 4;
    if (e0 + 3 < n_edges) {
        int4 r = *reinterpret_cast<const int4*>(row + e0);
        int4 c = *reinterpret_cast<const int4*>(col + e0);
        float4 lg;
        lg.x = p_row[r.x] + p_col[c.x];
        lg.y = p_row[r.y] + p_col[c.y];
        lg.z = p_row[r.z] + p_col[c.z];
        lg.w = p_row[r.w] + p_col[c.w];
        float4 w;
        w.x = 1.0f / (1.0f + expf(-lg.x));
        w.y = 1.0f / (1.0f + expf(-lg.y));
        w.z = 1.0f / (1.0f + expf(-lg.z));
        w.w = 1.0f / (1.0f + expf(-lg.w));
        *reinterpret_cast<float4*>(weights + e0) = w;
    } else {
        for (int e = e0; e < n_edges; ++e) {
            float l = p_row[row[e]] + p_col[col[e]];
            weights[e] = 1.0f / (1.0f + expf(-l));
        }
    }
}

// Kernel 3: out[e] = weights[e] * weights[fri[e]]. 4 edges/thread.
__global__ void edge_pair_kernel(const float* __restrict__ weights,
                                 const int* __restrict__ fri,
                                 float* __restrict__ out,
                                 int n_edges) {
    int e0 = (blockIdx.x * blockDim.x + threadIdx.x) * 4;
    if (e0 + 3 < n_edges) {
        float4 w = *reinterpret_cast<const float4*>(weights + e0);
        int4 idx = *reinterpret_cast<const int4*>(fri + e0);
        float4 o;
        o.x = w.x * weights[idx.x];
        o.y = w.y * weights[idx.y];
        o.z = w.z * weights[idx.z];
        o.w = w.w * weights[idx.w];
        *reinterpret_cast<float4*>(out + e0) = o;
    } else {
        for (int e = e0; e < n_edges; ++e) {
            out[e] = weights[e] * weights[fri[e]];
        }
    }
}

extern "C" void kernel_launch(void* const* d_in, const int* in_sizes, int n_in,
                              void* d_out, int out_size, void* d_ws, size_t ws_size,
                              hipStream_t stream) {
    const float* x     = (const float*)d_in[0];   // (N_NODES, 64) f32
    const float* w_lin = (const float*)d_in[1];   // (128,) f32
    const int*   eidx  = (const int*)d_in[2];     // (2, N_EDGES) int32
    const int*   fri   = (const int*)d_in[3];     // (N_EDGES,) int32

    const int n_nodes = in_sizes[0] / IN_CH;
    const int n_edges = in_sizes[3];

    const int* row = eidx;
    const int* col = eidx + n_edges;

    float* p_row   = (float*)d_ws;                 // n_nodes floats
    float* p_col   = p_row + n_nodes;              // n_nodes floats
    float* weights = p_col + n_nodes;              // n_edges floats
    float* out     = (float*)d_out;                // n_edges floats

    // Kernel 1: 16 threads per node
    {
        long long threads = (long long)n_nodes * 16;
        int block = 256;
        int grid = (int)((threads + block - 1) / block);
        node_dots_kernel<<<grid, block, 0, stream>>>(x, w_lin, p_row, p_col, n_nodes);
    }
    // Kernel 2: 4 edges per thread
    {
        int block = 256;
        int grid = (n_edges / 4 + block - 1) / block;
        edge_sigmoid_kernel<<<grid, block, 0, stream>>>(row, col, p_row, p_col, weights, n_edges);
    }
    // Kernel 3: 4 edges per thread
    {
        int block = 256;
        int grid = (n_edges / 4 + block - 1) / block;
        edge_pair_kernel<<<grid, block, 0, stream>>>(weights, fri, out, n_edges);
    }
}